// Round 10
// baseline (627.158 us; speedup 1.0000x reference)
//
#include <hip/hip_runtime.h>
#include <hip/hip_bf16.h>

using bf16   = __bf16;
using bf16x2 = __attribute__((ext_vector_type(2))) __bf16;
using bf16x4 = __attribute__((ext_vector_type(4))) __bf16;
using bf16x8 = __attribute__((ext_vector_type(8))) __bf16;
using f32x4  = __attribute__((ext_vector_type(4))) float;

constexpr int LAYERS = 4;
constexpr int BATCH  = 2;
constexpr int SEQ    = 1024;
constexpr int DIM    = 1024;
constexpr int FF     = 4096;
constexpr int HEADS  = 16;
constexpr int TOK    = BATCH * SEQ;   // 2048
constexpr int QKVN   = 3 * DIM;       // 3072
constexpr float EPS  = 1e-5f;

// async global->LDS, 16B per lane (HW: wave-uniform LDS base + lane*16)
__device__ __forceinline__ void gload_lds16(const void* g, void* l) {
    __builtin_amdgcn_global_load_lds(
        (const __attribute__((address_space(1))) void*)g,
        (__attribute__((address_space(3))) void*)l, 16, 0, 0);
}

// ---------------------------------------------------------------- LayerNorm
__global__ __launch_bounds__(256) void ln_kernel(
    const float* __restrict__ x, const float* __restrict__ g,
    const float* __restrict__ bt, bf16* __restrict__ out)
{
    __shared__ float red[8];
    const int row = blockIdx.x, t = threadIdx.x;
    const float4 v = ((const float4*)(x + (size_t)row * DIM))[t];

    float s = v.x + v.y + v.z + v.w;
    #pragma unroll
    for (int o = 32; o; o >>= 1) s += __shfl_down(s, o, 64);
    if ((t & 63) == 0) red[t >> 6] = s;
    __syncthreads();
    const float mean = (red[0] + red[1] + red[2] + red[3]) * (1.0f / DIM);

    const float dx = v.x - mean, dy = v.y - mean, dz = v.z - mean, dw = v.w - mean;
    float q = dx * dx + dy * dy + dz * dz + dw * dw;
    #pragma unroll
    for (int o = 32; o; o >>= 1) q += __shfl_down(q, o, 64);
    if ((t & 63) == 0) red[4 + (t >> 6)] = q;
    __syncthreads();
    const float var = (red[4] + red[5] + red[6] + red[7]) * (1.0f / DIM);
    const float rstd = rsqrtf(var + EPS);

    const float4 gg = ((const float4*)g)[t];
    const float4 bb = ((const float4*)bt)[t];
    bf16x4 o4;
    o4[0] = (bf16)(dx * rstd * gg.x + bb.x);
    o4[1] = (bf16)(dy * rstd * gg.y + bb.y);
    o4[2] = (bf16)(dz * rstd * gg.z + bb.z);
    o4[3] = (bf16)(dw * rstd * gg.w + bb.w);
    *(bf16x4*)(out + (size_t)row * DIM + t * 4) = o4;
}

// ------------------------- split-K combine (4 bf16 partials + bias), opt. LN
template<bool DO_LN>
__global__ __launch_bounds__(256) void lncomb_kernel(
    float* __restrict__ x, const bf16* __restrict__ p,
    const float* __restrict__ bias, const float* __restrict__ g,
    const float* __restrict__ bt, bf16* __restrict__ out)
{
    __shared__ float red[8];
    const int row = blockIdx.x, t = threadIdx.x;
    float4 v = ((const float4*)(x + (size_t)row * DIM))[t];
    const float4 bv = ((const float4*)bias)[t];
    float a0 = bv.x, a1 = bv.y, a2 = bv.z, a3 = bv.w;
    #pragma unroll
    for (int ks = 0; ks < 4; ++ks) {
        const bf16x4 pp = *(const bf16x4*)(p + (size_t)(ks * TOK + row) * DIM + t * 4);
        a0 += (float)pp[0]; a1 += (float)pp[1];
        a2 += (float)pp[2]; a3 += (float)pp[3];
    }
    v.x += a0; v.y += a1; v.z += a2; v.w += a3;
    ((float4*)(x + (size_t)row * DIM))[t] = v;
    if (!DO_LN) return;

    float s = v.x + v.y + v.z + v.w;
    #pragma unroll
    for (int o = 32; o; o >>= 1) s += __shfl_down(s, o, 64);
    if ((t & 63) == 0) red[t >> 6] = s;
    __syncthreads();
    const float mean = (red[0] + red[1] + red[2] + red[3]) * (1.0f / DIM);

    const float dx = v.x - mean, dy = v.y - mean, dz = v.z - mean, dw = v.w - mean;
    float q = dx * dx + dy * dy + dz * dz + dw * dw;
    #pragma unroll
    for (int o = 32; o; o >>= 1) q += __shfl_down(q, o, 64);
    if ((t & 63) == 0) red[4 + (t >> 6)] = q;
    __syncthreads();
    const float var = (red[4] + red[5] + red[6] + red[7]) * (1.0f / DIM);
    const float rstd = rsqrtf(var + EPS);

    const float4 gg = ((const float4*)g)[t];
    const float4 bb = ((const float4*)bt)[t];
    bf16x4 o4;
    o4[0] = (bf16)(dx * rstd * gg.x + bb.x);
    o4[1] = (bf16)(dy * rstd * gg.y + bb.y);
    o4[2] = (bf16)(dz * rstd * gg.z + bb.z);
    o4[3] = (bf16)(dw * rstd * gg.w + bb.w);
    *(bf16x4*)(out + (size_t)row * DIM + t * 4) = o4;
}

// ------------------------------ fused weight transpose+convert (one layer)
__global__ __launch_bounds__(256) void wtrans_all_kernel(
    const float* __restrict__ Wq, const float* __restrict__ Wk,
    const float* __restrict__ Wv, const float* __restrict__ Wo,
    const float* __restrict__ W1, const float* __restrict__ W2,
    bf16* __restrict__ wqkvt, bf16* __restrict__ wot,
    bf16* __restrict__ w1t, bf16* __restrict__ w2t)
{
    __shared__ float tile[32][33];
    const int bid = blockIdx.x;
    const float* W; bf16* Wt; int N, K, rowoff, bx, by;
    if (bid < 3072) {
        const int seg = bid >> 10, r = bid & 1023;
        W = (seg == 0) ? Wq : (seg == 1) ? Wk : Wv;
        Wt = wqkvt; N = DIM; K = DIM; rowoff = seg * DIM;
        bx = r & 31; by = r >> 5;
    } else if (bid < 4096) {
        const int r = bid - 3072;
        W = Wo; Wt = wot; N = DIM; K = DIM; rowoff = 0;
        bx = r & 31; by = r >> 5;
    } else if (bid < 8192) {
        const int r = bid - 4096;
        W = W1; Wt = w1t; N = FF; K = DIM; rowoff = 0;
        bx = r & 127; by = r >> 7;
    } else {
        const int r = bid - 8192;
        W = W2; Wt = w2t; N = DIM; K = FF; rowoff = 0;
        bx = r & 31; by = r >> 5;
    }
    const int bn = bx * 32, bk = by * 32;
    const int r = threadIdx.x >> 3, c4 = (threadIdx.x & 7) * 4;
    const float4 v = *(const float4*)(W + (size_t)(bk + r) * N + bn + c4);
    tile[r][c4 + 0] = v.x; tile[r][c4 + 1] = v.y;
    tile[r][c4 + 2] = v.z; tile[r][c4 + 3] = v.w;
    __syncthreads();
    bf16x4 o;
    #pragma unroll
    for (int j = 0; j < 4; ++j) o[j] = (bf16)tile[c4 + j][r];
    *(bf16x4*)(Wt + (size_t)(rowoff + bn + r) * K + bk + c4) = o;
}

// ---------------------------------------------------------------- GEMM
// C = A[M,Kfull](bf16) @ Bt(bf16 [N][Kfull]).  BM=BN=128, BK=32, 4 waves,
// 4x4 fragment acc per wave (0.5 KB LDS-read per MFMA -- LDS-BW optimal
// for this family).  2-buffer LDS (32 KB), both-sides chunk swizzle,
// SK-way split-K.  EPI 0: bf16. 1: +bias GELU bf16. 3: bf16 partial.
template<int EPI, int SK>
__global__ __launch_bounds__(256) void gemm_kernel(
    const bf16* __restrict__ A, const bf16* __restrict__ Bt,
    const float* __restrict__ bias, void* __restrict__ outv,
    int M, int N, int Kfull)
{
    __shared__ bf16 As[2][128 * 32];
    __shared__ bf16 Bs[2][128 * 32];

    const int t    = threadIdx.x;
    const int lane = t & 63;
    const int w    = t >> 6;
    const int wm   = (w >> 1) * 64;
    const int wn   = (w & 1) * 64;
    const int kg   = lane >> 4, lr = lane & 15;
    const int key  = lr & 3;

    const int nwg = gridDim.x;
    const int bid = (blockIdx.x & 7) * (nwg >> 3) + (blockIdx.x >> 3);
    const int nbn = N / 128, nbm = M / 128;
    const int ks  = (SK > 1) ? bid / (nbm * nbn) : 0;
    const int r   = (SK > 1) ? bid % (nbm * nbn) : bid;
    const int bm  = ((SK > 1) ? (r / nbn) : (r % nbm)) * 128;
    const int bn  = ((SK > 1) ? (r % nbn) : (r / nbm)) * 128;

    const int Ksl = Kfull / SK;
    const int kof = ks * Ksl;

    f32x4 acc[4][4] = {};

    // stage: logical LDS chunk (row, c) holds global k-chunk (c ^ (row&3))
    auto stage = [&](int buf, int k0) {
        #pragma unroll
        for (int it = 0; it < 2; ++it) {
            const int ci = it * 256 + t, row = ci >> 2, c = ci & 3;
            gload_lds16(A + (size_t)(bm + row) * Kfull + kof + k0 + ((c ^ (row & 3)) << 3),
                        &As[buf][ci * 8]);
        }
        #pragma unroll
        for (int it = 0; it < 2; ++it) {
            const int ci = it * 256 + t, row = ci >> 2, c = ci & 3;
            gload_lds16(Bt + (size_t)(bn + row) * Kfull + kof + k0 + ((c ^ (row & 3)) << 3),
                        &Bs[buf][ci * 8]);
        }
    };

    stage(0, 0);
    __syncthreads();

    int cur = 0;
    for (int k0 = 0; k0 < Ksl; k0 += 32) {
        if (k0 + 32 < Ksl) stage(cur ^ 1, k0 + 32);

        bf16x8 af[4], bfr[4];
        #pragma unroll
        for (int m = 0; m < 4; ++m) {
            const int row = wm + m * 16 + lr;
            af[m] = *(const bf16x8*)(&As[cur][row * 32 + ((kg ^ key) << 3)]);
        }
        #pragma unroll
        for (int n = 0; n < 4; ++n) {
            const int row = wn + n * 16 + lr;
            bfr[n] = *(const bf16x8*)(&Bs[cur][row * 32 + ((kg ^ key) << 3)]);
        }
        #pragma unroll
        for (int m = 0; m < 4; ++m)
            #pragma unroll
            for (int n = 0; n < 4; ++n)
                acc[m][n] = __builtin_amdgcn_mfma_f32_16x16x32_bf16(af[m], bfr[n], acc[m][n], 0, 0, 0);

        __syncthreads();
        cur ^= 1;
    }

    #pragma unroll
    for (int m = 0; m < 4; ++m) {
        const int row = bm + wm + m * 16 + kg * 4;
        #pragma unroll
        for (int n = 0; n < 4; ++n) {
            const int col = bn + wn + n * 16 + lr;
            #pragma unroll
            for (int j = 0; j < 4; ++j) {
                const float vv = acc[m][n][j];
                const size_t idx = (size_t)(row + j) * N + col;
                if (EPI == 0) {
                    ((bf16*)outv)[idx] = (bf16)vv;
                } else if (EPI == 1) {
                    const float z = vv + bias[col];
                    const float gl = 0.5f * z * (1.0f + erff(z * 0.70710678118654752f));
                    ((bf16*)outv)[idx] = (bf16)gl;
                } else {
                    ((bf16*)outv)[(size_t)ks * M * N + idx] = (bf16)vv;
                }
            }
        }
    }
}

// ------------------------------------------------- MFMA flash attention
// Swapped-operand scheme: S^T = mfma(K,Q) -> per-lane softmax (q = lane&15),
// P row-major in LDS (b64 writes), O^T = mfma(V^T, P).
__global__ __launch_bounds__(256) void attn_kernel(
    const bf16* __restrict__ qkv, bf16* __restrict__ od)
{
    __shared__ bf16 Ks[2][64][72];
    __shared__ bf16 Vt[2][64][64];   // [d][kv] physical, chunk-swizzled
    __shared__ bf16 Ps[4][16][72];   // per-wave P rows [q][kv]

    const int nwg = gridDim.x;       // 512
    const int bid = (blockIdx.x & 7) * (nwg >> 3) + (blockIdx.x >> 3);
    const int q0  = (bid & 15) * 64;
    const int bh  = bid >> 4;
    const int b   = bh >> 4, h = bh & 15;
    const int t   = threadIdx.x, w = t >> 6, lane = t & 63;
    const int kg  = lane >> 4, lr = lane & 15;

    const bf16* qbase = qkv + (size_t)b * SEQ * QKVN + h * 64;
    const bf16* kbase = qbase + DIM;
    const bf16* vbase = qbase + 2 * DIM;

    // Q fragment (wave's 16 rows), pre-scaled by 1/sqrt(64)=2^-3 (exact)
    bf16x8 qf0, qf1;
    {
        const bf16* qr = qbase + (size_t)(q0 + w * 16 + lr) * QKVN;
        qf0 = *(const bf16x8*)(qr + kg * 8);
        qf1 = *(const bf16x8*)(qr + 32 + kg * 8);
        #pragma unroll
        for (int j = 0; j < 8; ++j) {
            qf0[j] = (bf16)((float)qf0[j] * 0.125f);
            qf1[j] = (bf16)((float)qf1[j] * 0.125f);
        }
    }

    f32x4 o_acc[4] = {};
    float m_run = -1e30f, l_run = 0.f;

    const int rK = t >> 3, oK = (t & 7) * 8;   // K stage rows rK, rK+32
    const int rp = t >> 3, cV = t & 7;         // V stage rows 2rp,2rp+1

    bf16x8 kr0, kr1, vr0, vr1;
    auto loadKV = [&](int kb) {
        kr0 = *(const bf16x8*)(kbase + (size_t)(kb + rK) * QKVN + oK);
        kr1 = *(const bf16x8*)(kbase + (size_t)(kb + 32 + rK) * QKVN + oK);
        vr0 = *(const bf16x8*)(vbase + (size_t)(kb + 2 * rp) * QKVN + cV * 8);
        vr1 = *(const bf16x8*)(vbase + (size_t)(kb + 2 * rp + 1) * QKVN + cV * 8);
    };
    auto storeKV = [&](int buf) {
        *(bf16x8*)&Ks[buf][rK][oK]      = kr0;
        *(bf16x8*)&Ks[buf][32 + rK][oK] = kr1;
        #pragma unroll
        for (int j = 0; j < 8; ++j) {
            bf16x2 p; p[0] = vr0[j]; p[1] = vr1[j];
            const int d  = cV * 8 + j;
            const int dw = (((rp >> 2) ^ (j ^ cV)) << 2) | (rp & 3);
            *(bf16x2*)((char*)&Vt[buf][d][0] + dw * 4) = p;
        }
    };

    loadKV(0);
    storeKV(0);
    __syncthreads();

    int cur = 0;
    for (int kb = 0; kb < SEQ; kb += 64) {
        const bool more = (kb + 64 < SEQ);
        if (more) loadKV(kb + 64);            // issue early

        // ---- S^T = K·Q^T: lane holds 16 scores of q-row (q0+w*16+lr)
        f32x4 s[4] = {};
        __builtin_amdgcn_s_setprio(1);
        #pragma unroll
        for (int n = 0; n < 4; ++n) {
            const bf16x8 kf0 = *(const bf16x8*)&Ks[cur][n * 16 + lr][kg * 8];
            const bf16x8 kf1 = *(const bf16x8*)&Ks[cur][n * 16 + lr][32 + kg * 8];
            s[n] = __builtin_amdgcn_mfma_f32_16x16x32_bf16(kf0, qf0, s[n], 0, 0, 0);
            s[n] = __builtin_amdgcn_mfma_f32_16x16x32_bf16(kf1, qf1, s[n], 0, 0, 0);
        }
        __builtin_amdgcn_s_setprio(0);

        // ---- per-lane online softmax (2 shuffle steps across kg groups)
        float pmax = -1e30f;
        #pragma unroll
        for (int n = 0; n < 4; ++n)
            #pragma unroll
            for (int j = 0; j < 4; ++j) pmax = fmaxf(pmax, s[n][j]);
        pmax = fmaxf(pmax, __shfl_xor(pmax, 16, 64));
        pmax = fmaxf(pmax, __shfl_xor(pmax, 32, 64));

        if (!__all(pmax <= m_run + 8.0f)) {   // defer-max (exact)
            const float mn   = fmaxf(m_run, pmax);
            const float corr = __expf(m_run - mn);
            m_run = mn;
            l_run *= corr;
            #pragma unroll
            for (int nd = 0; nd < 4; ++nd)
                #pragma unroll
                for (int j = 0; j < 4; ++j) o_acc[nd][j] *= corr;
        }

        float rs = 0.f;
        #pragma unroll
        for (int n = 0; n < 4; ++n)
            #pragma unroll
            for (int j = 0; j < 4; ++j) {
                const float e = __expf(s[n][j] - m_run);
                s[n][j] = e; rs += e;
            }
        rs += __shfl_xor(rs, 16, 64);
        rs += __shfl_xor(rs, 32, 64);
        l_run += rs;

        // ---- P -> LDS row-major (b64 writes, 2-way free)
        #pragma unroll
        for (int n = 0; n < 4; ++n) {
            bf16x4 pw;
            #pragma unroll
            for (int j = 0; j < 4; ++j) pw[j] = (bf16)s[n][j];
            *(bf16x4*)&Ps[w][lr][n * 16 + kg * 4] = pw;
        }

        // ---- O^T += V^T · P  (A = V^T frag, B = P frag)
        const bf16x8 pf0 = *(const bf16x8*)&Ps[w][lr][kg * 8];
        const bf16x8 pf1 = *(const bf16x8*)&Ps[w][lr][32 + kg * 8];
        __builtin_amdgcn_s_setprio(1);
        #pragma unroll
        for (int nd = 0; nd < 4; ++nd) {
            const int d   = nd * 16 + lr;
            const int keyv = (d ^ (d >> 3)) & 7;
            const bf16x8 vf0 = *(const bf16x8*)((const char*)&Vt[cur][d][0] + ((kg ^ keyv) << 4));
            const bf16x8 vf1 = *(const bf16x8*)((const char*)&Vt[cur][d][0] + (((4 + kg) ^ keyv) << 4));
            o_acc[nd] = __builtin_amdgcn_mfma_f32_16x16x32_bf16(vf0, pf0, o_acc[nd], 0, 0, 0);
            o_acc[nd] = __builtin_amdgcn_mfma_f32_16x16x32_bf16(vf1, pf1, o_acc[nd], 0, 0, 0);
        }
        __builtin_amdgcn_s_setprio(0);

        if (more) storeKV(cur ^ 1);           // write late
        __syncthreads();
        cur ^= 1;
    }

    // ---- finalize: O[q][d], q = q0+w*16+lr, d = nd*16+kg*4+j
    const float inv = 1.0f / l_run;
    bf16* ob = od + (size_t)(b * SEQ + q0 + w * 16 + lr) * DIM + h * 64;
    #pragma unroll
    for (int nd = 0; nd < 4; ++nd) {
        bf16x4 o4;
        #pragma unroll
        for (int j = 0; j < 4; ++j) o4[j] = (bf16)(o_acc[nd][j] * inv);
        *(bf16x4*)(ob + nd * 16 + kg * 4) = o4;
    }
}

// ---------------------------------------------------------------- launch
extern "C" void kernel_launch(void* const* d_in, const int* in_sizes, int n_in,
                              void* d_out, int out_size, void* d_ws, size_t ws_size,
                              hipStream_t stream)
{
    const float* x    = (const float*)d_in[0];
    const float* ln1w = (const float*)d_in[1];
    const float* ln1b = (const float*)d_in[2];
    const float* Wq   = (const float*)d_in[3];
    const float* Wk   = (const float*)d_in[4];
    const float* Wv   = (const float*)d_in[5];
    const float* Wo   = (const float*)d_in[6];
    const float* bo   = (const float*)d_in[7];
    const float* ln2w = (const float*)d_in[8];
    const float* ln2b = (const float*)d_in[9];
    const float* W1   = (const float*)d_in[10];
    const float* b1   = (const float*)d_in[11];
    const float* W2   = (const float*)d_in[12];
    const float* b2   = (const float*)d_in[13];

    char* ws = (char*)d_ws;
    float* xbuf  = (float*)(ws);                 // 8 MB f32 residual
    bf16*  hbuf  = (bf16*)(ws + (8ull  << 20));  // 4 MB
    bf16*  qkvb  = (bf16*)(ws + (12ull << 20));  // 12 MB
    bf16*  obuf  = (bf16*)(ws + (24ull << 20));  // 4 MB
    bf16*  gbuf  = (bf16*)(ws + (28ull << 20));  // 16 MB
    bf16*  wqkvt = (bf16*)(ws + (44ull << 20));  // 6 MB  [3072][1024]
    bf16*  wot   = (bf16*)(ws + (50ull << 20));  // 2 MB  [1024][1024]
    bf16*  w1t   = (bf16*)(ws + (52ull << 20));  // 8 MB  [4096][1024]
    bf16*  w2t   = (bf16*)(ws + (60ull << 20));  // 8 MB  [1024][4096]
    bf16*  pbuf  = (bf16*)(ws + (68ull << 20));  // 16 MB [4][TOK][DIM] bf16

    hipMemcpyAsync(xbuf, x, (size_t)TOK * DIM * sizeof(float),
                   hipMemcpyDeviceToDevice, stream);

    const size_t DD = (size_t)DIM * DIM, DF = (size_t)DIM * FF;
    for (int l = 0; l < LAYERS; ++l) {
        wtrans_all_kernel<<<12288, 256, 0, stream>>>(
            Wq + l * DD, Wk + l * DD, Wv + l * DD, Wo + l * DD,
            W1 + l * DF, W2 + l * DF, wqkvt, wot, w1t, w2t);

        if (l == 0)
            ln_kernel<<<TOK, 256, 0, stream>>>(xbuf, ln1w, ln1b, hbuf);

        gemm_kernel<0, 1><<<16 * 24, 256, 0, stream>>>(
            hbuf, wqkvt, nullptr, qkvb, TOK, QKVN, DIM);

        attn_kernel<<<512, 256, 0, stream>>>(qkvb, obuf);

        gemm_kernel<3, 4><<<16 * 8 * 4, 256, 0, stream>>>(
            obuf, wot, nullptr, pbuf, TOK, DIM, DIM);

        lncomb_kernel<true><<<TOK, 256, 0, stream>>>(
            xbuf, pbuf, bo + l * DIM, ln2w + l * DIM, ln2b + l * DIM, hbuf);

        gemm_kernel<1, 1><<<16 * 32, 256, 0, stream>>>(
            hbuf, w1t, b1 + l * FF, gbuf, TOK, FF, DIM);

        gemm_kernel<3, 4><<<16 * 8 * 4, 256, 0, stream>>>(
            gbuf, w2t, nullptr, pbuf, TOK, DIM, FF);

        if (l + 1 < LAYERS)
            lncomb_kernel<true><<<TOK, 256, 0, stream>>>(
                xbuf, pbuf, b2 + l * DIM, ln1w + (l + 1) * DIM, ln1b + (l + 1) * DIM, hbuf);
        else
            lncomb_kernel<false><<<TOK, 256, 0, stream>>>(
                xbuf, pbuf, b2 + l * DIM, nullptr, nullptr, nullptr);
    }

    hipMemcpyAsync(d_out, xbuf, (size_t)TOK * DIM * sizeof(float),
                   hipMemcpyDeviceToDevice, stream);
}

// Round 11
// 606.787 us; speedup vs baseline: 1.0336x; 1.0336x over previous
//
#include <hip/hip_runtime.h>
#include <hip/hip_bf16.h>

using bf16   = __bf16;
using bf16x2 = __attribute__((ext_vector_type(2))) __bf16;
using bf16x4 = __attribute__((ext_vector_type(4))) __bf16;
using bf16x8 = __attribute__((ext_vector_type(8))) __bf16;
using f32x4  = __attribute__((ext_vector_type(4))) float;

constexpr int LAYERS = 4;
constexpr int BATCH  = 2;
constexpr int SEQ    = 1024;
constexpr int DIM    = 1024;
constexpr int FF     = 4096;
constexpr int HEADS  = 16;
constexpr int TOK    = BATCH * SEQ;   // 2048
constexpr int QKVN   = 3 * DIM;       // 3072
constexpr float EPS  = 1e-5f;

// async global->LDS, 16B per lane (HW: wave-uniform LDS base + lane*16)
__device__ __forceinline__ void gload_lds16(const void* g, void* l) {
    __builtin_amdgcn_global_load_lds(
        (const __attribute__((address_space(1))) void*)g,
        (__attribute__((address_space(3))) void*)l, 16, 0, 0);
}

// ---------------------------------------------------------------- LayerNorm
__global__ __launch_bounds__(256) void ln_kernel(
    const float* __restrict__ x, const float* __restrict__ g,
    const float* __restrict__ bt, bf16* __restrict__ out)
{
    __shared__ float red[8];
    const int row = blockIdx.x, t = threadIdx.x;
    const float4 v = ((const float4*)(x + (size_t)row * DIM))[t];

    float s = v.x + v.y + v.z + v.w;
    #pragma unroll
    for (int o = 32; o; o >>= 1) s += __shfl_down(s, o, 64);
    if ((t & 63) == 0) red[t >> 6] = s;
    __syncthreads();
    const float mean = (red[0] + red[1] + red[2] + red[3]) * (1.0f / DIM);

    const float dx = v.x - mean, dy = v.y - mean, dz = v.z - mean, dw = v.w - mean;
    float q = dx * dx + dy * dy + dz * dz + dw * dw;
    #pragma unroll
    for (int o = 32; o; o >>= 1) q += __shfl_down(q, o, 64);
    if ((t & 63) == 0) red[4 + (t >> 6)] = q;
    __syncthreads();
    const float var = (red[4] + red[5] + red[6] + red[7]) * (1.0f / DIM);
    const float rstd = rsqrtf(var + EPS);

    const float4 gg = ((const float4*)g)[t];
    const float4 bb = ((const float4*)bt)[t];
    bf16x4 o4;
    o4[0] = (bf16)(dx * rstd * gg.x + bb.x);
    o4[1] = (bf16)(dy * rstd * gg.y + bb.y);
    o4[2] = (bf16)(dz * rstd * gg.z + bb.z);
    o4[3] = (bf16)(dw * rstd * gg.w + bb.w);
    *(bf16x4*)(out + (size_t)row * DIM + t * 4) = o4;
}

// ------------------------- split-K combine (4 bf16 partials + bias), opt. LN
template<bool DO_LN>
__global__ __launch_bounds__(256) void lncomb_kernel(
    float* __restrict__ x, const bf16* __restrict__ p,
    const float* __restrict__ bias, const float* __restrict__ g,
    const float* __restrict__ bt, bf16* __restrict__ out)
{
    __shared__ float red[8];
    const int row = blockIdx.x, t = threadIdx.x;
    float4 v = ((const float4*)(x + (size_t)row * DIM))[t];
    const float4 bv = ((const float4*)bias)[t];
    float a0 = bv.x, a1 = bv.y, a2 = bv.z, a3 = bv.w;
    #pragma unroll
    for (int ks = 0; ks < 4; ++ks) {
        const bf16x4 pp = *(const bf16x4*)(p + (size_t)(ks * TOK + row) * DIM + t * 4);
        a0 += (float)pp[0]; a1 += (float)pp[1];
        a2 += (float)pp[2]; a3 += (float)pp[3];
    }
    v.x += a0; v.y += a1; v.z += a2; v.w += a3;
    ((float4*)(x + (size_t)row * DIM))[t] = v;
    if (!DO_LN) return;

    float s = v.x + v.y + v.z + v.w;
    #pragma unroll
    for (int o = 32; o; o >>= 1) s += __shfl_down(s, o, 64);
    if ((t & 63) == 0) red[t >> 6] = s;
    __syncthreads();
    const float mean = (red[0] + red[1] + red[2] + red[3]) * (1.0f / DIM);

    const float dx = v.x - mean, dy = v.y - mean, dz = v.z - mean, dw = v.w - mean;
    float q = dx * dx + dy * dy + dz * dz + dw * dw;
    #pragma unroll
    for (int o = 32; o; o >>= 1) q += __shfl_down(q, o, 64);
    if ((t & 63) == 0) red[4 + (t >> 6)] = q;
    __syncthreads();
    const float var = (red[4] + red[5] + red[6] + red[7]) * (1.0f / DIM);
    const float rstd = rsqrtf(var + EPS);

    const float4 gg = ((const float4*)g)[t];
    const float4 bb = ((const float4*)bt)[t];
    bf16x4 o4;
    o4[0] = (bf16)(dx * rstd * gg.x + bb.x);
    o4[1] = (bf16)(dy * rstd * gg.y + bb.y);
    o4[2] = (bf16)(dz * rstd * gg.z + bb.z);
    o4[3] = (bf16)(dw * rstd * gg.w + bb.w);
    *(bf16x4*)(out + (size_t)row * DIM + t * 4) = o4;
}

// ------------------------------ fused weight transpose+convert (one layer)
// 64x64 tiles, bf16x8 (16B) stores.  3072 blocks.
__global__ __launch_bounds__(256) void wtrans_all_kernel(
    const float* __restrict__ Wq, const float* __restrict__ Wk,
    const float* __restrict__ Wv, const float* __restrict__ Wo,
    const float* __restrict__ W1, const float* __restrict__ W2,
    bf16* __restrict__ wqkvt, bf16* __restrict__ wot,
    bf16* __restrict__ w1t, bf16* __restrict__ w2t)
{
    __shared__ float tile[64][65];
    const int bid = blockIdx.x;
    const float* W; bf16* Wt; int N, K, rowoff, bx, by;
    if (bid < 768) {
        const int seg = bid >> 8, r = bid & 255;
        W = (seg == 0) ? Wq : (seg == 1) ? Wk : Wv;
        Wt = wqkvt; N = DIM; K = DIM; rowoff = seg * DIM;
        bx = r & 15; by = r >> 4;
    } else if (bid < 1024) {
        const int r = bid - 768;
        W = Wo; Wt = wot; N = DIM; K = DIM; rowoff = 0;
        bx = r & 15; by = r >> 4;
    } else if (bid < 2048) {
        const int r = bid - 1024;
        W = W1; Wt = w1t; N = FF; K = DIM; rowoff = 0;
        bx = r & 63; by = r >> 6;
    } else {
        const int r = bid - 2048;
        W = W2; Wt = w2t; N = DIM; K = FF; rowoff = 0;
        bx = r & 15; by = r >> 4;
    }
    const int bn = bx * 64, bk = by * 64;
    {
        const int r16 = threadIdx.x >> 4, c4 = (threadIdx.x & 15) * 4;
        #pragma unroll
        for (int i = 0; i < 4; ++i) {
            const int kr = r16 + i * 16;
            const float4 v = *(const float4*)(W + (size_t)(bk + kr) * N + bn + c4);
            tile[kr][c4 + 0] = v.x; tile[kr][c4 + 1] = v.y;
            tile[kr][c4 + 2] = v.z; tile[kr][c4 + 3] = v.w;
        }
    }
    __syncthreads();
    {
        const int n = threadIdx.x >> 2, ch = threadIdx.x & 3;
        #pragma unroll
        for (int i = 0; i < 2; ++i) {
            const int k0 = (ch + i * 4) * 8;
            bf16x8 o;
            #pragma unroll
            for (int j = 0; j < 8; ++j) o[j] = (bf16)tile[k0 + j][n];
            *(bf16x8*)(Wt + (size_t)(rowoff + bn + n) * K + bk + k0) = o;
        }
    }
}

// ---------------------------------------------------------------- GEMM
// C = A[M,Kfull](bf16) @ Bt(bf16 [N][Kfull]).  BM=128, BN=64, BK=32.
// 2-buffer LDS (24 KB), both-sides chunk swizzle key=(row>>1)&3
// (conflict-free at 64B row stride: (row&1, key) spans all 8 bank starts).
// SK-way split-K.  EPI 0: bf16. 1: +bias GELU bf16. 3: bf16 partial.
template<int EPI, int SK>
__global__ __launch_bounds__(256) void gemm_kernel(
    const bf16* __restrict__ A, const bf16* __restrict__ Bt,
    const float* __restrict__ bias, void* __restrict__ outv,
    int M, int N, int Kfull)
{
    constexpr int MR = 2;
    __shared__ bf16 As[2][128 * 32];
    __shared__ bf16 Bs[2][64 * 32];

    const int t    = threadIdx.x;
    const int lane = t & 63;
    const int w    = t >> 6;
    const int wm   = w * 32;
    const int kg   = lane >> 4, lr = lane & 15;
    const int key  = (lr >> 1) & 3;

    const int nwg = gridDim.x;
    const int bid = (blockIdx.x & 7) * (nwg >> 3) + (blockIdx.x >> 3);
    const int nbn = N / 64, nbm = M / 128;
    const int ks  = (SK > 1) ? bid / (nbm * nbn) : 0;
    const int r   = (SK > 1) ? bid % (nbm * nbn) : bid;
    const int bm  = ((SK > 1) ? (r / nbn) : (r % nbm)) * 128;
    const int bn  = ((SK > 1) ? (r % nbn) : (r / nbm)) * 64;

    const int Ksl = Kfull / SK;
    const int kof = ks * Ksl;

    f32x4 acc[MR][4] = {};

    // stage: logical LDS chunk (row, c) holds global k-chunk c ^ ((row>>1)&3)
    auto stage = [&](int buf, int k0) {
        #pragma unroll
        for (int it = 0; it < 2; ++it) {
            const int ci = it * 256 + t, row = ci >> 2, c = ci & 3;
            gload_lds16(A + (size_t)(bm + row) * Kfull + kof + k0 + ((c ^ ((row >> 1) & 3)) << 3),
                        &As[buf][ci * 8]);
        }
        {
            const int ci = t, row = ci >> 2, c = ci & 3;
            gload_lds16(Bt + (size_t)(bn + row) * Kfull + kof + k0 + ((c ^ ((row >> 1) & 3)) << 3),
                        &Bs[buf][ci * 8]);
        }
    };

    stage(0, 0);
    __syncthreads();

    int cur = 0;
    for (int k0 = 0; k0 < Ksl; k0 += 32) {
        if (k0 + 32 < Ksl) stage(cur ^ 1, k0 + 32);

        bf16x8 af[MR], bfr[4];
        #pragma unroll
        for (int m = 0; m < MR; ++m) {
            const int row = wm + m * 16 + lr;
            af[m] = *(const bf16x8*)(&As[cur][row * 32 + ((kg ^ key) << 3)]);
        }
        #pragma unroll
        for (int n = 0; n < 4; ++n) {
            const int row = n * 16 + lr;
            bfr[n] = *(const bf16x8*)(&Bs[cur][row * 32 + ((kg ^ key) << 3)]);
        }
        #pragma unroll
        for (int m = 0; m < MR; ++m)
            #pragma unroll
            for (int n = 0; n < 4; ++n)
                acc[m][n] = __builtin_amdgcn_mfma_f32_16x16x32_bf16(af[m], bfr[n], acc[m][n], 0, 0, 0);

        __syncthreads();
        cur ^= 1;
    }

    #pragma unroll
    for (int m = 0; m < MR; ++m) {
        const int row = bm + wm + m * 16 + kg * 4;
        #pragma unroll
        for (int n = 0; n < 4; ++n) {
            const int col = bn + n * 16 + lr;
            #pragma unroll
            for (int j = 0; j < 4; ++j) {
                const float vv = acc[m][n][j];
                const size_t idx = (size_t)(row + j) * N + col;
                if (EPI == 0) {
                    ((bf16*)outv)[idx] = (bf16)vv;
                } else if (EPI == 1) {
                    const float z = vv + bias[col];
                    const float gl = 0.5f * z * (1.0f + erff(z * 0.70710678118654752f));
                    ((bf16*)outv)[idx] = (bf16)gl;
                } else {
                    ((bf16*)outv)[(size_t)ks * M * N + idx] = (bf16)vv;
                }
            }
        }
    }
}

// ------------------------------------------------- MFMA flash attention
// Swapped-operand scheme: S^T = mfma(K,Q) -> per-lane softmax (q = lane&15),
// P row-major in LDS (b64 writes), O^T = mfma(V^T, P).
// K staged via gload_lds16 (pre-swizzled source, key=row&7); V reg-staged.
__global__ __launch_bounds__(256) void attn_kernel(
    const bf16* __restrict__ qkv, bf16* __restrict__ od)
{
    __shared__ bf16 Ks[2][64 * 64];  // row*64 + swz-chunk*8
    __shared__ bf16 Vt[2][64][64];   // [d][kv] physical, chunk-swizzled
    __shared__ bf16 Ps[4][16][72];   // per-wave P rows [q][kv]

    const int nwg = gridDim.x;       // 512
    const int bid = (blockIdx.x & 7) * (nwg >> 3) + (blockIdx.x >> 3);
    const int q0  = (bid & 15) * 64;
    const int bh  = bid >> 4;
    const int b   = bh >> 4, h = bh & 15;
    const int t   = threadIdx.x, w = t >> 6, lane = t & 63;
    const int kg  = lane >> 4, lr = lane & 15;

    const bf16* qbase = qkv + (size_t)b * SEQ * QKVN + h * 64;
    const bf16* kbase = qbase + DIM;
    const bf16* vbase = qbase + 2 * DIM;

    // Q fragment (wave's 16 rows), pre-scaled by 1/sqrt(64)=2^-3 (exact)
    bf16x8 qf0, qf1;
    {
        const bf16* qr = qbase + (size_t)(q0 + w * 16 + lr) * QKVN;
        qf0 = *(const bf16x8*)(qr + kg * 8);
        qf1 = *(const bf16x8*)(qr + 32 + kg * 8);
        #pragma unroll
        for (int j = 0; j < 8; ++j) {
            qf0[j] = (bf16)((float)qf0[j] * 0.125f);
            qf1[j] = (bf16)((float)qf1[j] * 0.125f);
        }
    }

    f32x4 o_acc[4] = {};
    float m_run = -1e30f, l_run = 0.f;

    const int rp = t >> 3, cV = t & 7;         // V stage rows 2rp,2rp+1

    bf16x8 vr0, vr1;
    auto loadV = [&](int kb) {                 // issue BEFORE stageK (older vmcnt)
        vr0 = *(const bf16x8*)(vbase + (size_t)(kb + 2 * rp) * QKVN + cV * 8);
        vr1 = *(const bf16x8*)(vbase + (size_t)(kb + 2 * rp + 1) * QKVN + cV * 8);
    };
    auto stageK = [&](int buf, int kb) {       // async DMA, swizzled source
        #pragma unroll
        for (int i = 0; i < 2; ++i) {
            const int ci = i * 256 + t, row = ci >> 3, c = ci & 7;
            gload_lds16(kbase + (size_t)(kb + row) * QKVN + ((c ^ (row & 7)) << 3),
                        &Ks[buf][ci * 8]);
        }
    };
    auto storeV = [&](int buf) {
        #pragma unroll
        for (int j = 0; j < 8; ++j) {
            bf16x2 p; p[0] = vr0[j]; p[1] = vr1[j];
            const int d  = cV * 8 + j;
            const int dw = (((rp >> 2) ^ (j ^ cV)) << 2) | (rp & 3);
            *(bf16x2*)((char*)&Vt[buf][d][0] + dw * 4) = p;
        }
    };

    loadV(0);
    stageK(0, 0);
    storeV(0);
    __syncthreads();

    int cur = 0;
    for (int kb = 0; kb < SEQ; kb += 64) {
        const bool more = (kb + 64 < SEQ);
        if (more) { loadV(kb + 64); stageK(cur ^ 1, kb + 64); }

        // ---- S^T = K·Q^T: lane holds 16 scores of q-row (q0+w*16+lr)
        f32x4 s[4] = {};
        __builtin_amdgcn_s_setprio(1);
        #pragma unroll
        for (int n = 0; n < 4; ++n) {
            const int row = n * 16 + lr;
            const bf16x8 kf0 = *(const bf16x8*)&Ks[cur][row * 64 + ((kg ^ (lr & 7)) << 3)];
            const bf16x8 kf1 = *(const bf16x8*)&Ks[cur][row * 64 + (((4 + kg) ^ (lr & 7)) << 3)];
            s[n] = __builtin_amdgcn_mfma_f32_16x16x32_bf16(kf0, qf0, s[n], 0, 0, 0);
            s[n] = __builtin_amdgcn_mfma_f32_16x16x32_bf16(kf1, qf1, s[n], 0, 0, 0);
        }
        __builtin_amdgcn_s_setprio(0);

        // ---- per-lane online softmax (2 shuffle steps across kg groups)
        float pmax = -1e30f;
        #pragma unroll
        for (int n = 0; n < 4; ++n)
            #pragma unroll
            for (int j = 0; j < 4; ++j) pmax = fmaxf(pmax, s[n][j]);
        pmax = fmaxf(pmax, __shfl_xor(pmax, 16, 64));
        pmax = fmaxf(pmax, __shfl_xor(pmax, 32, 64));

        if (!__all(pmax <= m_run + 8.0f)) {   // defer-max (exact)
            const float mn   = fmaxf(m_run, pmax);
            const float corr = __expf(m_run - mn);
            m_run = mn;
            l_run *= corr;
            #pragma unroll
            for (int nd = 0; nd < 4; ++nd)
                #pragma unroll
                for (int j = 0; j < 4; ++j) o_acc[nd][j] *= corr;
        }

        float rs = 0.f;
        #pragma unroll
        for (int n = 0; n < 4; ++n)
            #pragma unroll
            for (int j = 0; j < 4; ++j) {
                const float e = __expf(s[n][j] - m_run);
                s[n][j] = e; rs += e;
            }
        rs += __shfl_xor(rs, 16, 64);
        rs += __shfl_xor(rs, 32, 64);
        l_run += rs;

        // ---- P -> LDS row-major (b64 writes, 2-way free)
        #pragma unroll
        for (int n = 0; n < 4; ++n) {
            bf16x4 pw;
            #pragma unroll
            for (int j = 0; j < 4; ++j) pw[j] = (bf16)s[n][j];
            *(bf16x4*)&Ps[w][lr][n * 16 + kg * 4] = pw;
        }

        // ---- O^T += V^T · P  (A = V^T frag, B = P frag)
        const bf16x8 pf0 = *(const bf16x8*)&Ps[w][lr][kg * 8];
        const bf16x8 pf1 = *(const bf16x8*)&Ps[w][lr][32 + kg * 8];
        __builtin_amdgcn_s_setprio(1);
        #pragma unroll
        for (int nd = 0; nd < 4; ++nd) {
            const int d   = nd * 16 + lr;
            const int keyv = (d ^ (d >> 3)) & 7;
            const bf16x8 vf0 = *(const bf16x8*)((const char*)&Vt[cur][d][0] + ((kg ^ keyv) << 4));
            const bf16x8 vf1 = *(const bf16x8*)((const char*)&Vt[cur][d][0] + (((4 + kg) ^ keyv) << 4));
            o_acc[nd] = __builtin_amdgcn_mfma_f32_16x16x32_bf16(vf0, pf0, o_acc[nd], 0, 0, 0);
            o_acc[nd] = __builtin_amdgcn_mfma_f32_16x16x32_bf16(vf1, pf1, o_acc[nd], 0, 0, 0);
        }
        __builtin_amdgcn_s_setprio(0);

        if (more) storeV(cur ^ 1);            // write late
        __syncthreads();
        cur ^= 1;
    }

    // ---- finalize: O[q][d], q = q0+w*16+lr, d = nd*16+kg*4+j
    const float inv = 1.0f / l_run;
    bf16* ob = od + (size_t)(b * SEQ + q0 + w * 16 + lr) * DIM + h * 64;
    #pragma unroll
    for (int nd = 0; nd < 4; ++nd) {
        bf16x4 o4;
        #pragma unroll
        for (int j = 0; j < 4; ++j) o4[j] = (bf16)(o_acc[nd][j] * inv);
        *(bf16x4*)(ob + nd * 16 + kg * 4) = o4;
    }
}

// ---------------------------------------------------------------- launch
extern "C" void kernel_launch(void* const* d_in, const int* in_sizes, int n_in,
                              void* d_out, int out_size, void* d_ws, size_t ws_size,
                              hipStream_t stream)
{
    const float* x    = (const float*)d_in[0];
    const float* ln1w = (const float*)d_in[1];
    const float* ln1b = (const float*)d_in[2];
    const float* Wq   = (const float*)d_in[3];
    const float* Wk   = (const float*)d_in[4];
    const float* Wv   = (const float*)d_in[5];
    const float* Wo   = (const float*)d_in[6];
    const float* bo   = (const float*)d_in[7];
    const float* ln2w = (const float*)d_in[8];
    const float* ln2b = (const float*)d_in[9];
    const float* W1   = (const float*)d_in[10];
    const float* b1   = (const float*)d_in[11];
    const float* W2   = (const float*)d_in[12];
    const float* b2   = (const float*)d_in[13];

    char* ws = (char*)d_ws;
    float* xbuf  = (float*)(ws);                 // 8 MB f32 residual
    bf16*  hbuf  = (bf16*)(ws + (8ull  << 20));  // 4 MB
    bf16*  qkvb  = (bf16*)(ws + (12ull << 20));  // 12 MB
    bf16*  obuf  = (bf16*)(ws + (24ull << 20));  // 4 MB
    bf16*  gbuf  = (bf16*)(ws + (28ull << 20));  // 16 MB
    bf16*  wqkvt = (bf16*)(ws + (44ull << 20));  // 6 MB  [3072][1024]
    bf16*  wot   = (bf16*)(ws + (50ull << 20));  // 2 MB  [1024][1024]
    bf16*  w1t   = (bf16*)(ws + (52ull << 20));  // 8 MB  [4096][1024]
    bf16*  w2t   = (bf16*)(ws + (60ull << 20));  // 8 MB  [1024][4096]
    bf16*  pbuf  = (bf16*)(ws + (68ull << 20));  // 16 MB [4][TOK][DIM] bf16

    hipMemcpyAsync(xbuf, x, (size_t)TOK * DIM * sizeof(float),
                   hipMemcpyDeviceToDevice, stream);

    const size_t DD = (size_t)DIM * DIM, DF = (size_t)DIM * FF;
    for (int l = 0; l < LAYERS; ++l) {
        wtrans_all_kernel<<<3072, 256, 0, stream>>>(
            Wq + l * DD, Wk + l * DD, Wv + l * DD, Wo + l * DD,
            W1 + l * DF, W2 + l * DF, wqkvt, wot, w1t, w2t);

        if (l == 0)
            ln_kernel<<<TOK, 256, 0, stream>>>(xbuf, ln1w, ln1b, hbuf);

        gemm_kernel<0, 1><<<16 * 48, 256, 0, stream>>>(
            hbuf, wqkvt, nullptr, qkvb, TOK, QKVN, DIM);

        attn_kernel<<<512, 256, 0, stream>>>(qkvb, obuf);

        gemm_kernel<3, 4><<<16 * 16 * 4, 256, 0, stream>>>(
            obuf, wot, nullptr, pbuf, TOK, DIM, DIM);

        lncomb_kernel<true><<<TOK, 256, 0, stream>>>(
            xbuf, pbuf, bo + l * DIM, ln2w + l * DIM, ln2b + l * DIM, hbuf);

        gemm_kernel<1, 1><<<16 * 64, 256, 0, stream>>>(
            hbuf, w1t, b1 + l * FF, gbuf, TOK, FF, DIM);

        gemm_kernel<3, 4><<<16 * 16 * 4, 256, 0, stream>>>(
            gbuf, w2t, nullptr, pbuf, TOK, DIM, FF);

        if (l + 1 < LAYERS)
            lncomb_kernel<true><<<TOK, 256, 0, stream>>>(
                xbuf, pbuf, b2 + l * DIM, ln1w + (l + 1) * DIM, ln1b + (l + 1) * DIM, hbuf);
        else
            lncomb_kernel<false><<<TOK, 256, 0, stream>>>(
                xbuf, pbuf, b2 + l * DIM, nullptr, nullptr, nullptr);
    }

    hipMemcpyAsync(d_out, xbuf, (size_t)TOK * DIM * sizeof(float),
                   hipMemcpyDeviceToDevice, stream);
}

// Round 12
// 586.127 us; speedup vs baseline: 1.0700x; 1.0352x over previous
//
#include <hip/hip_runtime.h>
#include <hip/hip_bf16.h>

using bf16   = __bf16;
using bf16x2 = __attribute__((ext_vector_type(2))) __bf16;
using bf16x4 = __attribute__((ext_vector_type(4))) __bf16;
using bf16x8 = __attribute__((ext_vector_type(8))) __bf16;
using f32x4  = __attribute__((ext_vector_type(4))) float;

constexpr int LAYERS = 4;
constexpr int BATCH  = 2;
constexpr int SEQ    = 1024;
constexpr int DIM    = 1024;
constexpr int FF     = 4096;
constexpr int HEADS  = 16;
constexpr int TOK    = BATCH * SEQ;   // 2048
constexpr int QKVN   = 3 * DIM;       // 3072
constexpr float EPS  = 1e-5f;

// async global->LDS, 16B per lane (HW: wave-uniform LDS base + lane*16)
__device__ __forceinline__ void gload_lds16(const void* g, void* l) {
    __builtin_amdgcn_global_load_lds(
        (const __attribute__((address_space(1))) void*)g,
        (__attribute__((address_space(3))) void*)l, 16, 0, 0);
}

// ---------------------------------------------------------------- LayerNorm
__global__ __launch_bounds__(256) void ln_kernel(
    const float* __restrict__ x, const float* __restrict__ g,
    const float* __restrict__ bt, bf16* __restrict__ out)
{
    __shared__ float red[8];
    const int row = blockIdx.x, t = threadIdx.x;
    const float4 v = ((const float4*)(x + (size_t)row * DIM))[t];

    float s = v.x + v.y + v.z + v.w;
    #pragma unroll
    for (int o = 32; o; o >>= 1) s += __shfl_down(s, o, 64);
    if ((t & 63) == 0) red[t >> 6] = s;
    __syncthreads();
    const float mean = (red[0] + red[1] + red[2] + red[3]) * (1.0f / DIM);

    const float dx = v.x - mean, dy = v.y - mean, dz = v.z - mean, dw = v.w - mean;
    float q = dx * dx + dy * dy + dz * dz + dw * dw;
    #pragma unroll
    for (int o = 32; o; o >>= 1) q += __shfl_down(q, o, 64);
    if ((t & 63) == 0) red[4 + (t >> 6)] = q;
    __syncthreads();
    const float var = (red[4] + red[5] + red[6] + red[7]) * (1.0f / DIM);
    const float rstd = rsqrtf(var + EPS);

    const float4 gg = ((const float4*)g)[t];
    const float4 bb = ((const float4*)bt)[t];
    bf16x4 o4;
    o4[0] = (bf16)(dx * rstd * gg.x + bb.x);
    o4[1] = (bf16)(dy * rstd * gg.y + bb.y);
    o4[2] = (bf16)(dz * rstd * gg.z + bb.z);
    o4[3] = (bf16)(dw * rstd * gg.w + bb.w);
    *(bf16x4*)(out + (size_t)row * DIM + t * 4) = o4;
}

// ------------------------- split-K combine (4 bf16 partials + bias), opt. LN
template<bool DO_LN>
__global__ __launch_bounds__(256) void lncomb_kernel(
    float* __restrict__ x, const bf16* __restrict__ p,
    const float* __restrict__ bias, const float* __restrict__ g,
    const float* __restrict__ bt, bf16* __restrict__ out)
{
    __shared__ float red[8];
    const int row = blockIdx.x, t = threadIdx.x;
    float4 v = ((const float4*)(x + (size_t)row * DIM))[t];
    const float4 bv = ((const float4*)bias)[t];
    float a0 = bv.x, a1 = bv.y, a2 = bv.z, a3 = bv.w;
    #pragma unroll
    for (int ks = 0; ks < 4; ++ks) {
        const bf16x4 pp = *(const bf16x4*)(p + (size_t)(ks * TOK + row) * DIM + t * 4);
        a0 += (float)pp[0]; a1 += (float)pp[1];
        a2 += (float)pp[2]; a3 += (float)pp[3];
    }
    v.x += a0; v.y += a1; v.z += a2; v.w += a3;
    ((float4*)(x + (size_t)row * DIM))[t] = v;
    if (!DO_LN) return;

    float s = v.x + v.y + v.z + v.w;
    #pragma unroll
    for (int o = 32; o; o >>= 1) s += __shfl_down(s, o, 64);
    if ((t & 63) == 0) red[t >> 6] = s;
    __syncthreads();
    const float mean = (red[0] + red[1] + red[2] + red[3]) * (1.0f / DIM);

    const float dx = v.x - mean, dy = v.y - mean, dz = v.z - mean, dw = v.w - mean;
    float q = dx * dx + dy * dy + dz * dz + dw * dw;
    #pragma unroll
    for (int o = 32; o; o >>= 1) q += __shfl_down(q, o, 64);
    if ((t & 63) == 0) red[4 + (t >> 6)] = q;
    __syncthreads();
    const float var = (red[4] + red[5] + red[6] + red[7]) * (1.0f / DIM);
    const float rstd = rsqrtf(var + EPS);

    const float4 gg = ((const float4*)g)[t];
    const float4 bb = ((const float4*)bt)[t];
    bf16x4 o4;
    o4[0] = (bf16)(dx * rstd * gg.x + bb.x);
    o4[1] = (bf16)(dy * rstd * gg.y + bb.y);
    o4[2] = (bf16)(dz * rstd * gg.z + bb.z);
    o4[3] = (bf16)(dw * rstd * gg.w + bb.w);
    *(bf16x4*)(out + (size_t)row * DIM + t * 4) = o4;
}

// ------------------------------ fused weight transpose+convert (one layer)
// 64x64 tiles, bf16x8 (16B) stores.  3072 blocks.
__global__ __launch_bounds__(256) void wtrans_all_kernel(
    const float* __restrict__ Wq, const float* __restrict__ Wk,
    const float* __restrict__ Wv, const float* __restrict__ Wo,
    const float* __restrict__ W1, const float* __restrict__ W2,
    bf16* __restrict__ wqkvt, bf16* __restrict__ wot,
    bf16* __restrict__ w1t, bf16* __restrict__ w2t)
{
    __shared__ float tile[64][65];
    const int bid = blockIdx.x;
    const float* W; bf16* Wt; int N, K, rowoff, bx, by;
    if (bid < 768) {
        const int seg = bid >> 8, r = bid & 255;
        W = (seg == 0) ? Wq : (seg == 1) ? Wk : Wv;
        Wt = wqkvt; N = DIM; K = DIM; rowoff = seg * DIM;
        bx = r & 15; by = r >> 4;
    } else if (bid < 1024) {
        const int r = bid - 768;
        W = Wo; Wt = wot; N = DIM; K = DIM; rowoff = 0;
        bx = r & 15; by = r >> 4;
    } else if (bid < 2048) {
        const int r = bid - 1024;
        W = W1; Wt = w1t; N = FF; K = DIM; rowoff = 0;
        bx = r & 63; by = r >> 6;
    } else {
        const int r = bid - 2048;
        W = W2; Wt = w2t; N = DIM; K = FF; rowoff = 0;
        bx = r & 15; by = r >> 4;
    }
    const int bn = bx * 64, bk = by * 64;
    {
        const int r16 = threadIdx.x >> 4, c4 = (threadIdx.x & 15) * 4;
        #pragma unroll
        for (int i = 0; i < 4; ++i) {
            const int kr = r16 + i * 16;
            const float4 v = *(const float4*)(W + (size_t)(bk + kr) * N + bn + c4);
            tile[kr][c4 + 0] = v.x; tile[kr][c4 + 1] = v.y;
            tile[kr][c4 + 2] = v.z; tile[kr][c4 + 3] = v.w;
        }
    }
    __syncthreads();
    {
        const int n = threadIdx.x >> 2, ch = threadIdx.x & 3;
        #pragma unroll
        for (int i = 0; i < 2; ++i) {
            const int k0 = (ch + i * 4) * 8;
            bf16x8 o;
            #pragma unroll
            for (int j = 0; j < 8; ++j) o[j] = (bf16)tile[k0 + j][n];
            *(bf16x8*)(Wt + (size_t)(rowoff + bn + n) * K + bk + k0) = o;
        }
    }
}

// ------------------------------------------- GEMM, 128x128 tile, BK=64
// Round-7-proven staging (128B row stride, 8x8B chunks, XOR key=row&7 ->
// measured 0 bank conflicts) x round-10 tile (4 waves, 4x4 frags:
// 8 ds_read_b128 feed 16 MFMA).  2-buffer LDS (64 KB), SK-way split-K.
// EPI 0: bf16. 1: +bias GELU bf16. 3: bf16 partial at outv[ks*M*N].
template<int EPI, int SK>
__global__ __launch_bounds__(256) void gemm128_kernel(
    const bf16* __restrict__ A, const bf16* __restrict__ Bt,
    const float* __restrict__ bias, void* __restrict__ outv,
    int M, int N, int Kfull)
{
    __shared__ bf16 As[2][128 * 64];
    __shared__ bf16 Bs[2][128 * 64];

    const int t    = threadIdx.x;
    const int lane = t & 63;
    const int w    = t >> 6;
    const int wm   = (w >> 1) * 64;
    const int wn   = (w & 1) * 64;
    const int kg   = lane >> 4, lr = lane & 15;
    const int key  = lr & 7;

    const int nwg = gridDim.x;
    const int bid = (blockIdx.x & 7) * (nwg >> 3) + (blockIdx.x >> 3);
    const int nbn = N / 128, nbm = M / 128;
    const int ks  = (SK > 1) ? bid / (nbm * nbn) : 0;
    const int r   = (SK > 1) ? bid % (nbm * nbn) : bid;
    const int bm  = ((SK > 1) ? (r / nbn) : (r % nbm)) * 128;
    const int bn  = ((SK > 1) ? (r % nbn) : (r / nbm)) * 128;

    const int Ksl = Kfull / SK;
    const int kof = ks * Ksl;

    f32x4 acc[4][4] = {};

    // stage: logical LDS chunk (row, c) holds global k-chunk (c ^ (row&7))
    auto stage = [&](int buf, int k0) {
        #pragma unroll
        for (int it = 0; it < 4; ++it) {
            const int ci = it * 256 + t, row = ci >> 3, c = ci & 7;
            gload_lds16(A + (size_t)(bm + row) * Kfull + kof + k0 + ((c ^ (row & 7)) << 3),
                        &As[buf][ci * 8]);
        }
        #pragma unroll
        for (int it = 0; it < 4; ++it) {
            const int ci = it * 256 + t, row = ci >> 3, c = ci & 7;
            gload_lds16(Bt + (size_t)(bn + row) * Kfull + kof + k0 + ((c ^ (row & 7)) << 3),
                        &Bs[buf][ci * 8]);
        }
    };

    stage(0, 0);
    __syncthreads();

    int cur = 0;
    for (int k0 = 0; k0 < Ksl; k0 += 64) {
        if (k0 + 64 < Ksl) stage(cur ^ 1, k0 + 64);

        #pragma unroll
        for (int kk = 0; kk < 2; ++kk) {
            bf16x8 af[4], bfr[4];
            #pragma unroll
            for (int m = 0; m < 4; ++m) {
                const int row = wm + m * 16 + lr;
                af[m] = *(const bf16x8*)(&As[cur][row * 64 + (((kk * 4 + kg) ^ key) << 3)]);
            }
            #pragma unroll
            for (int n = 0; n < 4; ++n) {
                const int row = wn + n * 16 + lr;
                bfr[n] = *(const bf16x8*)(&Bs[cur][row * 64 + (((kk * 4 + kg) ^ key) << 3)]);
            }
            #pragma unroll
            for (int m = 0; m < 4; ++m)
                #pragma unroll
                for (int n = 0; n < 4; ++n)
                    acc[m][n] = __builtin_amdgcn_mfma_f32_16x16x32_bf16(af[m], bfr[n], acc[m][n], 0, 0, 0);
        }

        __syncthreads();
        cur ^= 1;
    }

    #pragma unroll
    for (int m = 0; m < 4; ++m) {
        const int row = bm + wm + m * 16 + kg * 4;
        #pragma unroll
        for (int n = 0; n < 4; ++n) {
            const int col = bn + wn + n * 16 + lr;
            #pragma unroll
            for (int j = 0; j < 4; ++j) {
                const float vv = acc[m][n][j];
                const size_t idx = (size_t)(row + j) * N + col;
                if (EPI == 0) {
                    ((bf16*)outv)[idx] = (bf16)vv;
                } else if (EPI == 1) {
                    const float z = vv + bias[col];
                    const float gl = 0.5f * z * (1.0f + erff(z * 0.70710678118654752f));
                    ((bf16*)outv)[idx] = (bf16)gl;
                } else {
                    ((bf16*)outv)[(size_t)ks * M * N + idx] = (bf16)vv;
                }
            }
        }
    }
}

// ---------------------------------------------------- GEMM, 128x64, BK=32
// (kept for Wo, whose split-K slices are too short for BK=64 amortization)
template<int EPI, int SK>
__global__ __launch_bounds__(256) void gemm64_kernel(
    const bf16* __restrict__ A, const bf16* __restrict__ Bt,
    const float* __restrict__ bias, void* __restrict__ outv,
    int M, int N, int Kfull)
{
    constexpr int MR = 2;
    __shared__ bf16 As[2][128 * 32];
    __shared__ bf16 Bs[2][64 * 32];

    const int t    = threadIdx.x;
    const int lane = t & 63;
    const int w    = t >> 6;
    const int wm   = w * 32;
    const int kg   = lane >> 4, lr = lane & 15;
    const int key  = (lr >> 1) & 3;

    const int nwg = gridDim.x;
    const int bid = (blockIdx.x & 7) * (nwg >> 3) + (blockIdx.x >> 3);
    const int nbn = N / 64, nbm = M / 128;
    const int ks  = (SK > 1) ? bid / (nbm * nbn) : 0;
    const int r   = (SK > 1) ? bid % (nbm * nbn) : bid;
    const int bm  = ((SK > 1) ? (r / nbn) : (r % nbm)) * 128;
    const int bn  = ((SK > 1) ? (r % nbn) : (r / nbm)) * 64;

    const int Ksl = Kfull / SK;
    const int kof = ks * Ksl;

    f32x4 acc[MR][4] = {};

    auto stage = [&](int buf, int k0) {
        #pragma unroll
        for (int it = 0; it < 2; ++it) {
            const int ci = it * 256 + t, row = ci >> 2, c = ci & 3;
            gload_lds16(A + (size_t)(bm + row) * Kfull + kof + k0 + ((c ^ ((row >> 1) & 3)) << 3),
                        &As[buf][ci * 8]);
        }
        {
            const int ci = t, row = ci >> 2, c = ci & 3;
            gload_lds16(Bt + (size_t)(bn + row) * Kfull + kof + k0 + ((c ^ ((row >> 1) & 3)) << 3),
                        &Bs[buf][ci * 8]);
        }
    };

    stage(0, 0);
    __syncthreads();

    int cur = 0;
    for (int k0 = 0; k0 < Ksl; k0 += 32) {
        if (k0 + 32 < Ksl) stage(cur ^ 1, k0 + 32);

        bf16x8 af[MR], bfr[4];
        #pragma unroll
        for (int m = 0; m < MR; ++m) {
            const int row = wm + m * 16 + lr;
            af[m] = *(const bf16x8*)(&As[cur][row * 32 + ((kg ^ key) << 3)]);
        }
        #pragma unroll
        for (int n = 0; n < 4; ++n) {
            const int row = n * 16 + lr;
            bfr[n] = *(const bf16x8*)(&Bs[cur][row * 32 + ((kg ^ key) << 3)]);
        }
        #pragma unroll
        for (int m = 0; m < MR; ++m)
            #pragma unroll
            for (int n = 0; n < 4; ++n)
                acc[m][n] = __builtin_amdgcn_mfma_f32_16x16x32_bf16(af[m], bfr[n], acc[m][n], 0, 0, 0);

        __syncthreads();
        cur ^= 1;
    }

    #pragma unroll
    for (int m = 0; m < MR; ++m) {
        const int row = bm + wm + m * 16 + kg * 4;
        #pragma unroll
        for (int n = 0; n < 4; ++n) {
            const int col = bn + n * 16 + lr;
            #pragma unroll
            for (int j = 0; j < 4; ++j) {
                const float vv = acc[m][n][j];
                const size_t idx = (size_t)(row + j) * N + col;
                if (EPI == 0) {
                    ((bf16*)outv)[idx] = (bf16)vv;
                } else if (EPI == 1) {
                    const float z = vv + bias[col];
                    const float gl = 0.5f * z * (1.0f + erff(z * 0.70710678118654752f));
                    ((bf16*)outv)[idx] = (bf16)gl;
                } else {
                    ((bf16*)outv)[(size_t)ks * M * N + idx] = (bf16)vv;
                }
            }
        }
    }
}

// ------------------------------------------------- MFMA flash attention
// Swapped-operand scheme: S^T = mfma(K,Q) -> per-lane softmax (q = lane&15),
// P row-major in LDS (b64 writes), O^T = mfma(V^T, P).
// K staged via gload_lds16 (pre-swizzled source, key=row&7); V reg-staged.
__global__ __launch_bounds__(256) void attn_kernel(
    const bf16* __restrict__ qkv, bf16* __restrict__ od)
{
    __shared__ bf16 Ks[2][64 * 64];  // row*64 + swz-chunk*8
    __shared__ bf16 Vt[2][64][64];   // [d][kv] physical, chunk-swizzled
    __shared__ bf16 Ps[4][16][72];   // per-wave P rows [q][kv]

    const int nwg = gridDim.x;       // 512
    const int bid = (blockIdx.x & 7) * (nwg >> 3) + (blockIdx.x >> 3);
    const int q0  = (bid & 15) * 64;
    const int bh  = bid >> 4;
    const int b   = bh >> 4, h = bh & 15;
    const int t   = threadIdx.x, w = t >> 6, lane = t & 63;
    const int kg  = lane >> 4, lr = lane & 15;

    const bf16* qbase = qkv + (size_t)b * SEQ * QKVN + h * 64;
    const bf16* kbase = qbase + DIM;
    const bf16* vbase = qbase + 2 * DIM;

    bf16x8 qf0, qf1;
    {
        const bf16* qr = qbase + (size_t)(q0 + w * 16 + lr) * QKVN;
        qf0 = *(const bf16x8*)(qr + kg * 8);
        qf1 = *(const bf16x8*)(qr + 32 + kg * 8);
        #pragma unroll
        for (int j = 0; j < 8; ++j) {
            qf0[j] = (bf16)((float)qf0[j] * 0.125f);
            qf1[j] = (bf16)((float)qf1[j] * 0.125f);
        }
    }

    f32x4 o_acc[4] = {};
    float m_run = -1e30f, l_run = 0.f;

    const int rp = t >> 3, cV = t & 7;

    bf16x8 vr0, vr1;
    auto loadV = [&](int kb) {
        vr0 = *(const bf16x8*)(vbase + (size_t)(kb + 2 * rp) * QKVN + cV * 8);
        vr1 = *(const bf16x8*)(vbase + (size_t)(kb + 2 * rp + 1) * QKVN + cV * 8);
    };
    auto stageK = [&](int buf, int kb) {
        #pragma unroll
        for (int i = 0; i < 2; ++i) {
            const int ci = i * 256 + t, row = ci >> 3, c = ci & 7;
            gload_lds16(kbase + (size_t)(kb + row) * QKVN + ((c ^ (row & 7)) << 3),
                        &Ks[buf][ci * 8]);
        }
    };
    auto storeV = [&](int buf) {
        #pragma unroll
        for (int j = 0; j < 8; ++j) {
            bf16x2 p; p[0] = vr0[j]; p[1] = vr1[j];
            const int d  = cV * 8 + j;
            const int dw = (((rp >> 2) ^ (j ^ cV)) << 2) | (rp & 3);
            *(bf16x2*)((char*)&Vt[buf][d][0] + dw * 4) = p;
        }
    };

    loadV(0);
    stageK(0, 0);
    storeV(0);
    __syncthreads();

    int cur = 0;
    for (int kb = 0; kb < SEQ; kb += 64) {
        const bool more = (kb + 64 < SEQ);
        if (more) { loadV(kb + 64); stageK(cur ^ 1, kb + 64); }

        f32x4 s[4] = {};
        __builtin_amdgcn_s_setprio(1);
        #pragma unroll
        for (int n = 0; n < 4; ++n) {
            const int row = n * 16 + lr;
            const bf16x8 kf0 = *(const bf16x8*)&Ks[cur][row * 64 + ((kg ^ (lr & 7)) << 3)];
            const bf16x8 kf1 = *(const bf16x8*)&Ks[cur][row * 64 + (((4 + kg) ^ (lr & 7)) << 3)];
            s[n] = __builtin_amdgcn_mfma_f32_16x16x32_bf16(kf0, qf0, s[n], 0, 0, 0);
            s[n] = __builtin_amdgcn_mfma_f32_16x16x32_bf16(kf1, qf1, s[n], 0, 0, 0);
        }
        __builtin_amdgcn_s_setprio(0);

        float pmax = -1e30f;
        #pragma unroll
        for (int n = 0; n < 4; ++n)
            #pragma unroll
            for (int j = 0; j < 4; ++j) pmax = fmaxf(pmax, s[n][j]);
        pmax = fmaxf(pmax, __shfl_xor(pmax, 16, 64));
        pmax = fmaxf(pmax, __shfl_xor(pmax, 32, 64));

        if (!__all(pmax <= m_run + 8.0f)) {
            const float mn   = fmaxf(m_run, pmax);
            const float corr = __expf(m_run - mn);
            m_run = mn;
            l_run *= corr;
            #pragma unroll
            for (int nd = 0; nd < 4; ++nd)
                #pragma unroll
                for (int j = 0; j < 4; ++j) o_acc[nd][j] *= corr;
        }

        float rs = 0.f;
        #pragma unroll
        for (int n = 0; n < 4; ++n)
            #pragma unroll
            for (int j = 0; j < 4; ++j) {
                const float e = __expf(s[n][j] - m_run);
                s[n][j] = e; rs += e;
            }
        rs += __shfl_xor(rs, 16, 64);
        rs += __shfl_xor(rs, 32, 64);
        l_run += rs;

        #pragma unroll
        for (int n = 0; n < 4; ++n) {
            bf16x4 pw;
            #pragma unroll
            for (int j = 0; j < 4; ++j) pw[j] = (bf16)s[n][j];
            *(bf16x4*)&Ps[w][lr][n * 16 + kg * 4] = pw;
        }

        const bf16x8 pf0 = *(const bf16x8*)&Ps[w][lr][kg * 8];
        const bf16x8 pf1 = *(const bf16x8*)&Ps[w][lr][32 + kg * 8];
        __builtin_amdgcn_s_setprio(1);
        #pragma unroll
        for (int nd = 0; nd < 4; ++nd) {
            const int d   = nd * 16 + lr;
            const int keyv = (d ^ (d >> 3)) & 7;
            const bf16x8 vf0 = *(const bf16x8*)((const char*)&Vt[cur][d][0] + ((kg ^ keyv) << 4));
            const bf16x8 vf1 = *(const bf16x8*)((const char*)&Vt[cur][d][0] + (((4 + kg) ^ keyv) << 4));
            o_acc[nd] = __builtin_amdgcn_mfma_f32_16x16x32_bf16(vf0, pf0, o_acc[nd], 0, 0, 0);
            o_acc[nd] = __builtin_amdgcn_mfma_f32_16x16x32_bf16(vf1, pf1, o_acc[nd], 0, 0, 0);
        }
        __builtin_amdgcn_s_setprio(0);

        if (more) storeV(cur ^ 1);
        __syncthreads();
        cur ^= 1;
    }

    const float inv = 1.0f / l_run;
    bf16* ob = od + (size_t)(b * SEQ + q0 + w * 16 + lr) * DIM + h * 64;
    #pragma unroll
    for (int nd = 0; nd < 4; ++nd) {
        bf16x4 o4;
        #pragma unroll
        for (int j = 0; j < 4; ++j) o4[j] = (bf16)(o_acc[nd][j] * inv);
        *(bf16x4*)(ob + nd * 16 + kg * 4) = o4;
    }
}

// ---------------------------------------------------------------- launch
extern "C" void kernel_launch(void* const* d_in, const int* in_sizes, int n_in,
                              void* d_out, int out_size, void* d_ws, size_t ws_size,
                              hipStream_t stream)
{
    const float* x    = (const float*)d_in[0];
    const float* ln1w = (const float*)d_in[1];
    const float* ln1b = (const float*)d_in[2];
    const float* Wq   = (const float*)d_in[3];
    const float* Wk   = (const float*)d_in[4];
    const float* Wv   = (const float*)d_in[5];
    const float* Wo   = (const float*)d_in[6];
    const float* bo   = (const float*)d_in[7];
    const float* ln2w = (const float*)d_in[8];
    const float* ln2b = (const float*)d_in[9];
    const float* W1   = (const float*)d_in[10];
    const float* b1   = (const float*)d_in[11];
    const float* W2   = (const float*)d_in[12];
    const float* b2   = (const float*)d_in[13];

    char* ws = (char*)d_ws;
    float* xbuf  = (float*)(ws);                 // 8 MB f32 residual
    bf16*  hbuf  = (bf16*)(ws + (8ull  << 20));  // 4 MB
    bf16*  qkvb  = (bf16*)(ws + (12ull << 20));  // 12 MB
    bf16*  obuf  = (bf16*)(ws + (24ull << 20));  // 4 MB
    bf16*  gbuf  = (bf16*)(ws + (28ull << 20));  // 16 MB
    bf16*  wqkvt = (bf16*)(ws + (44ull << 20));  // 6 MB  [3072][1024]
    bf16*  wot   = (bf16*)(ws + (50ull << 20));  // 2 MB  [1024][1024]
    bf16*  w1t   = (bf16*)(ws + (52ull << 20));  // 8 MB  [4096][1024]
    bf16*  w2t   = (bf16*)(ws + (60ull << 20));  // 8 MB  [1024][4096]
    bf16*  pbuf  = (bf16*)(ws + (68ull << 20));  // 16 MB [4][TOK][DIM] bf16

    hipMemcpyAsync(xbuf, x, (size_t)TOK * DIM * sizeof(float),
                   hipMemcpyDeviceToDevice, stream);

    const size_t DD = (size_t)DIM * DIM, DF = (size_t)DIM * FF;
    for (int l = 0; l < LAYERS; ++l) {
        wtrans_all_kernel<<<3072, 256, 0, stream>>>(
            Wq + l * DD, Wk + l * DD, Wv + l * DD, Wo + l * DD,
            W1 + l * DF, W2 + l * DF, wqkvt, wot, w1t, w2t);

        if (l == 0)
            ln_kernel<<<TOK, 256, 0, stream>>>(xbuf, ln1w, ln1b, hbuf);

        gemm128_kernel<0, 1><<<16 * 24, 256, 0, stream>>>(
            hbuf, wqkvt, nullptr, qkvb, TOK, QKVN, DIM);

        attn_kernel<<<512, 256, 0, stream>>>(qkvb, obuf);

        gemm64_kernel<3, 4><<<16 * 16 * 4, 256, 0, stream>>>(
            obuf, wot, nullptr, pbuf, TOK, DIM, DIM);

        lncomb_kernel<true><<<TOK, 256, 0, stream>>>(
            xbuf, pbuf, bo + l * DIM, ln2w + l * DIM, ln2b + l * DIM, hbuf);

        gemm128_kernel<1, 1><<<16 * 32, 256, 0, stream>>>(
            hbuf, w1t, b1 + l * FF, gbuf, TOK, FF, DIM);

        gemm128_kernel<3, 4><<<16 * 8 * 4, 256, 0, stream>>>(
            gbuf, w2t, nullptr, pbuf, TOK, DIM, FF);

        if (l + 1 < LAYERS)
            lncomb_kernel<true><<<TOK, 256, 0, stream>>>(
                xbuf, pbuf, b2 + l * DIM, ln1w + (l + 1) * DIM, ln1b + (l + 1) * DIM, hbuf);
        else
            lncomb_kernel<false><<<TOK, 256, 0, stream>>>(
                xbuf, pbuf, b2 + l * DIM, nullptr, nullptr, nullptr);
    }

    hipMemcpyAsync(d_out, xbuf, (size_t)TOK * DIM * sizeof(float),
                   hipMemcpyDeviceToDevice, stream);
}